// Round 1
// baseline (381.936 us; speedup 1.0000x reference)
//
#include <hip/hip_runtime.h>

// Problem constants
constexpr int CIN = 256;
constexpr int D   = 128;
constexpr int K   = 1024;
constexpr int HW  = 4096;   // 64*64
constexpr int NPIX = 65536; // B*H*W
constexpr int MT  = 64;     // pixels per workgroup
constexpr int ZSTR = 129;   // z_s row stride (conflict-free)
constexpr int KT  = 256;    // k-chunk
constexpr int ESTR = 33;    // e_s row stride (32 d-slice + 1)

// scratch: [0] = diff accumulator, [16..16+K) = ||e_k||^2
__device__ float g_scratch[16 + K];

__global__ void vq_init(const float* __restrict__ embed) {
    int k = blockIdx.x * 256 + threadIdx.x;
    if (k == 0) g_scratch[0] = 0.0f;
    if (k < K) {
        float s = 0.0f;
        for (int d = 0; d < D; ++d) {
            float v = embed[d * K + k];
            s += v * v;
        }
        g_scratch[16 + k] = s;
    }
}

__global__ __launch_bounds__(256, 2) void vq_main(
    const float* __restrict__ x, const float* __restrict__ conv_w,
    const float* __restrict__ conv_b, const float* __restrict__ embed,
    float* __restrict__ out)
{
    __shared__ float z_s[MT * ZSTR];   // 33024 B
    __shared__ float e_s[KT * ESTR];   // 33792 B (phase1 reuses as x_s/w_s)
    __shared__ float e2_s[K];          // 4096 B
    __shared__ int   idx_s[MT];
    __shared__ float red_s[4];

    const int t   = threadIdx.x;
    const int wg  = blockIdx.x;       // 0..1023
    const int n0  = wg * MT;
    const int b   = n0 >> 12;         // /4096
    const int hw0 = n0 & 4095;

    // codebook squared norms (produced by vq_init on this stream)
    for (int k = t; k < K; k += 256) e2_s[k] = g_scratch[16 + k];

    // ---------------- Phase 1: z = x^T * W + bias  (per-pixel 1x1 conv) ----
    {
        const int pg = t & 31;          // pixels {pg, pg+32}
        const int d0 = (t >> 5) * 16;   // 16 d-outputs per pixel
        float acc0[16], acc1[16];
        #pragma unroll
        for (int j = 0; j < 16; ++j) { acc0[j] = 0.0f; acc1[j] = 0.0f; }

        float* x_s = e_s;          // [32][64]
        float* w_s = e_s + 2048;   // [32][128]
        const float* xb = x + (size_t)b * CIN * HW + hw0;

        for (int c0 = 0; c0 < CIN; c0 += 32) {
            __syncthreads();
            #pragma unroll
            for (int i = 0; i < 8; ++i) {           // x tile [32][64]
                int idx = t + i * 256;
                x_s[idx] = xb[(size_t)(c0 + (idx >> 6)) * HW + (idx & 63)];
            }
            #pragma unroll
            for (int i = 0; i < 16; ++i) {          // w tile [32][128]
                int idx = t + i * 256;
                w_s[idx] = conv_w[(c0 + (idx >> 7)) * D + (idx & 127)];
            }
            __syncthreads();
            for (int c = 0; c < 32; ++c) {
                float xv0 = x_s[c * 64 + pg];
                float xv1 = x_s[c * 64 + pg + 32];
                const float4* wr = (const float4*)(w_s + c * 128 + d0);
                #pragma unroll
                for (int q = 0; q < 4; ++q) {
                    float4 wv = wr[q];
                    acc0[q*4+0] += xv0 * wv.x; acc0[q*4+1] += xv0 * wv.y;
                    acc0[q*4+2] += xv0 * wv.z; acc0[q*4+3] += xv0 * wv.w;
                    acc1[q*4+0] += xv1 * wv.x; acc1[q*4+1] += xv1 * wv.y;
                    acc1[q*4+2] += xv1 * wv.z; acc1[q*4+3] += xv1 * wv.w;
                }
            }
        }
        #pragma unroll
        for (int j = 0; j < 16; ++j) {
            float bb = conv_b[d0 + j];
            z_s[pg * ZSTR + d0 + j]        = acc0[j] + bb;
            z_s[(pg + 32) * ZSTR + d0 + j] = acc1[j] + bb;
        }
    }
    __syncthreads();

    // ---------------- Phase 2: argmin_k ( ||e_k||^2 - 2 z.e_k ) ------------
    const int kg   = t & 31;         // k within group-of-32
    const int prow = (t >> 5) * 8;   // 8 pixels per thread
    float minv[8]; int mini[8];
    #pragma unroll
    for (int i = 0; i < 8; ++i) { minv[i] = 3.4e38f; mini[i] = 0; }

    for (int kc = 0; kc < K; kc += KT) {       // 4 chunks of 256 k
        float acc[8][8];
        #pragma unroll
        for (int i = 0; i < 8; ++i)
            #pragma unroll
            for (int j = 0; j < 8; ++j) acc[i][j] = 0.0f;

        for (int ds = 0; ds < D; ds += 32) {   // 4 d-slices
            __syncthreads();
            // stage e_s[k][d] (transposed): thread t = k, 32 d each
            #pragma unroll
            for (int d = 0; d < 32; ++d)
                e_s[t * ESTR + d] = embed[(ds + d) * K + kc + t];
            __syncthreads();
            #pragma unroll 4
            for (int d = 0; d < 32; ++d) {
                float zv[8];
                #pragma unroll
                for (int i = 0; i < 8; ++i)
                    zv[i] = z_s[(prow + i) * ZSTR + ds + d];
                #pragma unroll
                for (int j = 0; j < 8; ++j) {
                    float ev = e_s[(kg + 32 * j) * ESTR + d];
                    #pragma unroll
                    for (int i = 0; i < 8; ++i) acc[i][j] += zv[i] * ev;
                }
            }
        }
        // running argmin (k ascending within thread; strict < = first index)
        #pragma unroll
        for (int j = 0; j < 8; ++j) {
            int k = kc + kg + 32 * j;
            float e2 = e2_s[k];
            #pragma unroll
            for (int i = 0; i < 8; ++i) {
                float s = e2 - 2.0f * acc[i][j];
                if (s < minv[i]) { minv[i] = s; mini[i] = k; }
            }
        }
    }

    // reduce across the 32 kg-lanes (lanes 0..31 / 32..63 are independent)
    #pragma unroll
    for (int i = 0; i < 8; ++i) {
        float m = minv[i]; int mi = mini[i];
        #pragma unroll
        for (int off = 16; off >= 1; off >>= 1) {
            float m2 = __shfl_xor(m, off, 64);
            int   i2 = __shfl_xor(mi, off, 64);
            if (m2 < m || (m2 == m && i2 < mi)) { m = m2; mi = i2; }
        }
        if (kg == 0) idx_s[prow + i] = mi;
    }
    __syncthreads();

    // ---------------- Epilogue: gather, transpose-write, MSE ---------------
    const int p   = t & 63;
    const int dq0 = (t >> 6) * 32;
    const int kstar = idx_s[p];
    float diffacc = 0.0f;

    if (t < 64) out[8388609 + n0 + t] = (float)idx_s[t];  // embed_ind as f32

    float* outq = out + (size_t)b * D * HW + hw0;         // [B,D,H,W]
    #pragma unroll 8
    for (int dd = 0; dd < 32; ++dd) {
        int d = dq0 + dd;
        float q  = embed[d * K + kstar];
        float zz = z_s[p * ZSTR + d];
        float df = q - zz;
        diffacc += df * df;
        outq[(size_t)d * HW + p] = q;
    }
    #pragma unroll
    for (int off = 32; off >= 1; off >>= 1)
        diffacc += __shfl_xor(diffacc, off, 64);
    if ((t & 63) == 0) red_s[t >> 6] = diffacc;
    __syncthreads();
    if (t == 0) atomicAdd(&g_scratch[0], red_s[0] + red_s[1] + red_s[2] + red_s[3]);
}

__global__ void vq_final(float* __restrict__ out) {
    out[8388608] = g_scratch[0] / 8388608.0f;
}

extern "C" void kernel_launch(void* const* d_in, const int* in_sizes, int n_in,
                              void* d_out, int out_size, void* d_ws, size_t ws_size,
                              hipStream_t stream) {
    const float* x      = (const float*)d_in[0];
    const float* conv_w = (const float*)d_in[1];
    const float* conv_b = (const float*)d_in[2];
    const float* embed  = (const float*)d_in[3];
    float* out = (float*)d_out;

    vq_init <<<4, 256, 0, stream>>>(embed);
    vq_main <<<1024, 256, 0, stream>>>(x, conv_w, conv_b, embed, out);
    vq_final<<<1, 1, 0, stream>>>(out);
}

// Round 2
// 181.023 us; speedup vs baseline: 2.1099x; 2.1099x over previous
//
#include <hip/hip_runtime.h>

typedef __attribute__((ext_vector_type(4))) float f32x4;
typedef __attribute__((ext_vector_type(8))) short bf16x8;

constexpr int CIN = 256;
constexpr int D   = 128;
constexpr int K   = 1024;
constexpr int HW  = 4096;    // 64*64
constexpr int MT  = 128;     // pixels per workgroup -> 512 wgs
constexpr int ZSTR = 132;    // z_s row stride in floats (16B-aligned rows)

// quantize [B,D,H,W] = 8388608 floats, diff at [8388608], indices at [8388609..]
constexpr int DIFF_OFF = 8388608;
constexpr int IDX_OFF  = 8388609;

// static device scratch (avoids d_ws size assumptions)
__device__ float g_scratch[16 + K];                     // [0]=diff acc, [16+k]=||e_k||^2
__device__ __align__(16) uint4 g_efrags[64 * 8 * 64];   // [kt][db*2+spl][lane] B-fragments
__device__ __align__(16) float g_embedT[K * D];         // embed transposed [K][D]

__device__ inline unsigned short f2bf(float f) {        // f32 -> bf16 RNE
    unsigned u = __float_as_uint(f);
    u = u + 0x7fff + ((u >> 16) & 1);
    return (unsigned short)(u >> 16);
}
__device__ inline float bf2f(unsigned short h) {
    return __uint_as_float(((unsigned)h) << 16);
}

__global__ void vq_init(const float* __restrict__ embed) {
    int k = blockIdx.x * 256 + threadIdx.x;
    if (k == 0) g_scratch[0] = 0.0f;
    if (k < K) {
        float s = 0.0f;
        for (int d = 0; d < D; ++d) { float v = embed[d * K + k]; s += v * v; }
        g_scratch[16 + k] = s;
    }
}

// embedT[k][d] = embed[d][k]  (coalesced read, scattered write; 512KB once)
__global__ void vq_prep2(const float* __restrict__ embed) {
    int i = blockIdx.x * 256 + threadIdx.x;   // 131072 total
    int d = i >> 10, k = i & 1023;
    g_embedT[k * D + d] = embed[i];
}

// Pre-swizzle e into MFMA B-fragment order, hi/lo bf16 split.
// Frag (kt,db,spl): lane l holds e[d = db*32 + (l>>4)*8 + j][k = kt*16 + (l&15)], j=0..7
__global__ void vq_prep(const float* __restrict__ embed) {
    int kt = blockIdx.x >> 2, db = blockIdx.x & 3;
    int l  = threadIdx.x;                       // 0..63
    int k  = kt * 16 + (l & 15);
    int d0 = db * 32 + (l >> 4) * 8;
    unsigned short hi[8], lo[8];
    #pragma unroll
    for (int j = 0; j < 8; ++j) {
        float v = embed[(d0 + j) * K + k];
        hi[j] = f2bf(v);
        lo[j] = f2bf(v - bf2f(hi[j]));
    }
    uint4 H, L;
    H.x = (unsigned)hi[0] | ((unsigned)hi[1] << 16);
    H.y = (unsigned)hi[2] | ((unsigned)hi[3] << 16);
    H.z = (unsigned)hi[4] | ((unsigned)hi[5] << 16);
    H.w = (unsigned)hi[6] | ((unsigned)hi[7] << 16);
    L.x = (unsigned)lo[0] | ((unsigned)lo[1] << 16);
    L.y = (unsigned)lo[2] | ((unsigned)lo[3] << 16);
    L.z = (unsigned)lo[4] | ((unsigned)lo[5] << 16);
    L.w = (unsigned)lo[6] | ((unsigned)lo[7] << 16);
    g_efrags[(kt * 8 + db * 2 + 0) * 64 + l] = H;
    g_efrags[(kt * 8 + db * 2 + 1) * 64 + l] = L;
}

__global__ __launch_bounds__(256, 2) void vq_main(
    const float* __restrict__ x, const float* __restrict__ conv_w,
    const float* __restrict__ conv_b, float* __restrict__ out)
{
    __shared__ __align__(16) float z_s[MT * ZSTR];   // 67584 B (f32 z, refinement source)
    __shared__ float e2_s[K];                        // 4096 B
    __shared__ int   t2i1[MT], t2i2[MT];             // top-2 candidate indices
    __shared__ float refv[256];                      // exact dists for 2 cands/px
    __shared__ int   ks_s[MT];
    __shared__ float red_s[4];

    const int t    = threadIdx.x;
    const int lane = t & 63;
    const int w    = t >> 6;
    const int wg   = blockIdx.x;        // 0..511
    const int n0   = wg * MT;
    const int b    = n0 >> 12;
    const int hw0  = n0 & 4095;

    for (int k = t; k < K; k += 256) e2_s[k] = g_scratch[16 + k];

    // ---------------- Phase 1: z = x^T W + bias (f32 VALU) ------------------
    {
        float* x_s = z_s;           // [32][128] overlay (freed before z write)
        float* w_s = z_s + 4096;    // [32][128]
        const float* xb = x + (size_t)b * CIN * HW + hw0;
        const int p4 = (t & 31) * 4;      // 4 consecutive pixels
        const int d0 = (t >> 5) * 16;     // 16 d-outputs
        float acc[4][16];
        #pragma unroll
        for (int i = 0; i < 4; ++i)
            #pragma unroll
            for (int j = 0; j < 16; ++j) acc[i][j] = 0.0f;

        for (int c0 = 0; c0 < CIN; c0 += 32) {
            __syncthreads();
            #pragma unroll
            for (int i = 0; i < 16; ++i) {
                int idx = t + i * 256;     // 4096 elems each
                x_s[idx] = xb[(size_t)(c0 + (idx >> 7)) * HW + (idx & 127)];
                w_s[idx] = conv_w[(c0 + (idx >> 7)) * D + (idx & 127)];
            }
            __syncthreads();
            #pragma unroll 8
            for (int c = 0; c < 32; ++c) {
                f32x4 xv = *(const f32x4*)&x_s[c * 128 + p4];
                const f32x4* wr = (const f32x4*)&w_s[c * 128 + d0];
                #pragma unroll
                for (int q = 0; q < 4; ++q) {
                    f32x4 wv = wr[q];
                    #pragma unroll
                    for (int i = 0; i < 4; ++i) {
                        acc[i][q*4+0] += xv[i] * wv[0];
                        acc[i][q*4+1] += xv[i] * wv[1];
                        acc[i][q*4+2] += xv[i] * wv[2];
                        acc[i][q*4+3] += xv[i] * wv[3];
                    }
                }
            }
        }
        __syncthreads();   // staging region dead; safe to write z
        float bb[16];
        #pragma unroll
        for (int j = 0; j < 16; ++j) bb[j] = conv_b[d0 + j];
        #pragma unroll
        for (int i = 0; i < 4; ++i)
            #pragma unroll
            for (int j = 0; j < 16; ++j)
                z_s[(p4 + i) * ZSTR + d0 + j] = acc[i][j] + bb[j];
    }
    __syncthreads();

    // ---------------- Phase 2: MFMA distance + top-2 argmin -----------------
    // A = split(-2*z) hi/lo; B = g_efrags; C init = ||e_k||^2  => C = dist
    const int pxb = w * 32;                 // wave owns 32 pixel rows
    bf16x8 Ahi[2][4], Alo[2][4];
    #pragma unroll
    for (int rb = 0; rb < 2; ++rb) {
        int px = pxb + rb * 16 + (lane & 15);
        #pragma unroll
        for (int db = 0; db < 4; ++db) {
            int d0f = db * 32 + (lane >> 4) * 8;
            const float* zp = &z_s[px * ZSTR + d0f];
            f32x4 a = *(const f32x4*)zp;
            f32x4 c = *(const f32x4*)(zp + 4);
            float vv[8] = {a[0],a[1],a[2],a[3],c[0],c[1],c[2],c[3]};
            bf16x8 h, l8;
            #pragma unroll
            for (int j = 0; j < 8; ++j) {
                float zv = -2.0f * vv[j];
                unsigned short hb = f2bf(zv);
                h[j]  = (short)hb;
                l8[j] = (short)f2bf(zv - bf2f(hb));
            }
            Ahi[rb][db] = h; Alo[rb][db] = l8;
        }
    }

    float v1[8], v2[8]; int i1[8], i2[8];
    #pragma unroll
    for (int q = 0; q < 8; ++q) { v1[q] = 3.4e38f; v2[q] = 3.4e38f; i1[q] = 0; i2[q] = 0; }

    const bf16x8* fr = reinterpret_cast<const bf16x8*>(g_efrags);
    for (int kt = 0; kt < 64; ++kt) {
        bf16x8 Bh[4], Bl[4];
        #pragma unroll
        for (int db = 0; db < 4; ++db) {
            Bh[db] = fr[(kt * 8 + db * 2 + 0) * 64 + lane];
            Bl[db] = fr[(kt * 8 + db * 2 + 1) * 64 + lane];
        }
        float e2v = e2_s[kt * 16 + (lane & 15)];
        f32x4 C0 = {e2v, e2v, e2v, e2v};
        f32x4 C1 = C0;
        #pragma unroll
        for (int db = 0; db < 4; ++db) {
            C0 = __builtin_amdgcn_mfma_f32_16x16x32_bf16(Ahi[0][db], Bh[db], C0, 0, 0, 0);
            C1 = __builtin_amdgcn_mfma_f32_16x16x32_bf16(Ahi[1][db], Bh[db], C1, 0, 0, 0);
            C0 = __builtin_amdgcn_mfma_f32_16x16x32_bf16(Alo[0][db], Bh[db], C0, 0, 0, 0);
            C1 = __builtin_amdgcn_mfma_f32_16x16x32_bf16(Alo[1][db], Bh[db], C1, 0, 0, 0);
            C0 = __builtin_amdgcn_mfma_f32_16x16x32_bf16(Ahi[0][db], Bl[db], C0, 0, 0, 0);
            C1 = __builtin_amdgcn_mfma_f32_16x16x32_bf16(Ahi[1][db], Bl[db], C1, 0, 0, 0);
        }
        int kk = kt * 16 + (lane & 15);
        #pragma unroll
        for (int rb = 0; rb < 2; ++rb) {
            f32x4 C = rb ? C1 : C0;     // rb unrolled -> folds
            #pragma unroll
            for (int r = 0; r < 4; ++r) {
                int q = rb * 4 + r;
                float s = C[r];
                bool lt1 = s < v1[q], lt2 = s < v2[q];
                v2[q] = lt1 ? v1[q] : (lt2 ? s  : v2[q]);
                i2[q] = lt1 ? i1[q] : (lt2 ? kk : i2[q]);
                v1[q] = lt1 ? s  : v1[q];
                i1[q] = lt1 ? kk : i1[q];
            }
        }
    }

    // exact top-2 merge across the 16 k-lanes of each row group
    #pragma unroll
    for (int off = 1; off < 16; off <<= 1) {
        #pragma unroll
        for (int q = 0; q < 8; ++q) {
            float b1 = __shfl_xor(v1[q], off); int bi1 = __shfl_xor(i1[q], off);
            float b2 = __shfl_xor(v2[q], off); int bi2 = __shfl_xor(i2[q], off);
            bool bf = (b1 < v1[q]) || (b1 == v1[q] && bi1 < i1[q]);
            float cv = bf ? v1[q] : b1;  int ci = bf ? i1[q] : bi1;  // loser's best
            float wv = bf ? b2 : v2[q];  int wi = bf ? bi2 : i2[q];  // winner's 2nd
            v1[q] = bf ? b1 : v1[q];     i1[q] = bf ? bi1 : i1[q];
            bool c2 = (cv < wv) || (cv == wv && ci < wi);
            v2[q] = c2 ? cv : wv;        i2[q] = c2 ? ci : wi;
        }
    }
    if ((lane & 15) == 0) {
        #pragma unroll
        for (int q = 0; q < 8; ++q) {
            int px = pxb + (q >> 2) * 16 + (lane >> 4) * 4 + (q & 3);
            t2i1[px] = i1[q]; t2i2[px] = i2[q];
        }
    }
    __syncthreads();

    // ---------------- Exact f32 refinement of the two candidates ------------
    {
        int px = t >> 1, cand = t & 1;
        int k = cand ? t2i2[px] : t2i1[px];
        const f32x4* ep = (const f32x4*)&g_embedT[k * D];
        const f32x4* zp = (const f32x4*)&z_s[px * ZSTR];
        float acc = 0.0f;
        #pragma unroll 8
        for (int d4 = 0; d4 < 32; ++d4) {
            f32x4 e = ep[d4], z = zp[d4];
            acc += e[0]*z[0] + e[1]*z[1] + e[2]*z[2] + e[3]*z[3];
        }
        refv[t] = e2_s[k] - 2.0f * acc;
    }
    __syncthreads();
    if (t < MT) {
        float va = refv[2*t], vb = refv[2*t+1];
        int k0 = t2i1[t], k1 = t2i2[t];
        bool p1 = (vb < va) || (vb == va && k1 < k0);  // first-index tie rule
        int ks = p1 ? k1 : k0;
        ks_s[t] = ks;
        out[IDX_OFF + n0 + t] = (float)ks;
    }
    __syncthreads();

    // ---------------- Epilogue: gather quantize, transpose-write, MSE -------
    {
        int px = t & 127, half = t >> 7;
        int ks = ks_s[px];
        const f32x4* ep = (const f32x4*)&g_embedT[ks * D + half * 64];
        const f32x4* zp = (const f32x4*)&z_s[px * ZSTR + half * 64];
        float* ob = out + (size_t)b * D * HW + hw0 + px;
        float da = 0.0f;
        #pragma unroll
        for (int d4 = 0; d4 < 16; ++d4) {
            f32x4 q4 = ep[d4], z4 = zp[d4];
            int d = half * 64 + d4 * 4;
            #pragma unroll
            for (int c = 0; c < 4; ++c) {
                ob[(size_t)(d + c) * HW] = q4[c];
                float df = q4[c] - z4[c];
                da += df * df;
            }
        }
        #pragma unroll
        for (int off = 32; off >= 1; off >>= 1) da += __shfl_xor(da, off);
        if (lane == 0) red_s[w] = da;
    }
    __syncthreads();
    if (t == 0) atomicAdd(&g_scratch[0], red_s[0] + red_s[1] + red_s[2] + red_s[3]);
}

__global__ void vq_final(float* __restrict__ out) {
    out[DIFF_OFF] = g_scratch[0] / 8388608.0f;
}

extern "C" void kernel_launch(void* const* d_in, const int* in_sizes, int n_in,
                              void* d_out, int out_size, void* d_ws, size_t ws_size,
                              hipStream_t stream) {
    const float* x      = (const float*)d_in[0];
    const float* conv_w = (const float*)d_in[1];
    const float* conv_b = (const float*)d_in[2];
    const float* embed  = (const float*)d_in[3];
    float* out = (float*)d_out;

    vq_init <<<4,   256, 0, stream>>>(embed);
    vq_prep2<<<512, 256, 0, stream>>>(embed);
    vq_prep <<<256, 64,  0, stream>>>(embed);
    vq_main <<<512, 256, 0, stream>>>(x, conv_w, conv_b, out);
    vq_final<<<1,   1,   0, stream>>>(out);
}

// Round 5
// 104.215 us; speedup vs baseline: 3.6649x; 1.7370x over previous
//
#include <hip/hip_runtime.h>

typedef __attribute__((ext_vector_type(4))) float f32x4;
typedef __attribute__((ext_vector_type(8))) short bf16x8;

constexpr int CIN = 256;
constexpr int D   = 128;
constexpr int K   = 1024;
constexpr int HW  = 4096;    // 64*64
constexpr int MT  = 128;     // pixels per workgroup -> 512 wgs (2/CU exactly)
constexpr int DIFF_OFF = 8388608;
constexpr int IDX_OFF  = 8388609;

// static device scratch
__device__ float g_scratch[16 + K];                       // [0]=diff acc, [16+k]=||e_k||^2
__device__ __align__(16) uint4 g_efrags[64 * 8 * 64];     // e B-frags [kt][dc*2+s][lane]
__device__ __align__(16) uint4 g_wfrags[8 * 8 * 3 * 64];  // W B-frags [cb][db][s3][lane]
__device__ __align__(16) float g_embedT[K * D];           // embed transposed [K][D]

__device__ inline unsigned short f2bf(float f) {          // f32 -> bf16 RNE
    unsigned u = __float_as_uint(f);
    u = u + 0x7fff + ((u >> 16) & 1);
    return (unsigned short)(u >> 16);
}
__device__ inline float bf2f(unsigned short h) {
    return __uint_as_float(((unsigned)h) << 16);
}
// triple split: v = a + b + c with residual ~2^-24 |v|
__device__ inline void split3(float v, short& a, short& b, short& c) {
    unsigned short h = f2bf(v); float r1 = v - bf2f(h);
    unsigned short m = f2bf(r1); float r2 = r1 - bf2f(m);
    a = (short)h; b = (short)m; c = (short)f2bf(r2);
}

__global__ void vq_init(const float* __restrict__ embed) {
    int k = blockIdx.x * 256 + threadIdx.x;
    if (k == 0) g_scratch[0] = 0.0f;
    if (k < K) {
        float s = 0.0f;
        for (int d = 0; d < D; ++d) { float v = embed[d * K + k]; s += v * v; }
        g_scratch[16 + k] = s;
    }
}

// embedT via LDS-tiled transpose (coalesced read AND write)
__global__ void vq_prep2(const float* __restrict__ embed) {
    __shared__ float tile[32][33];
    int kb = blockIdx.x >> 2, db = blockIdx.x & 3;
    int t = threadIdx.x, tk = t & 31, td = t >> 5;
    #pragma unroll
    for (int dd = 0; dd < 4; ++dd)
        tile[td * 4 + dd][tk] = embed[(size_t)(db * 32 + td * 4 + dd) * K + kb * 32 + tk];
    __syncthreads();
    #pragma unroll
    for (int dd = 0; dd < 4; ++dd)
        g_embedT[(size_t)(kb * 32 + td * 4 + dd) * D + db * 32 + tk] = tile[tk][td * 4 + dd];
}

// e into MFMA B-fragment order, hi/lo bf16 split (2-way; approx pass only)
// Frag (kt,dc,s): lane l holds e[d = dc*32 + (l>>4)*8 + j][k = kt*16 + (l&15)]
__global__ void vq_prep(const float* __restrict__ embed) {
    int kt = blockIdx.x >> 2, dc = blockIdx.x & 3;
    int l  = threadIdx.x;
    int k  = kt * 16 + (l & 15);
    int d0 = dc * 32 + (l >> 4) * 8;
    unsigned short hi[8], lo[8];
    #pragma unroll
    for (int j = 0; j < 8; ++j) {
        float v = embed[(size_t)(d0 + j) * K + k];
        hi[j] = f2bf(v);
        lo[j] = f2bf(v - bf2f(hi[j]));
    }
    uint4 H, L;
    H.x = (unsigned)hi[0] | ((unsigned)hi[1] << 16);
    H.y = (unsigned)hi[2] | ((unsigned)hi[3] << 16);
    H.z = (unsigned)hi[4] | ((unsigned)hi[5] << 16);
    H.w = (unsigned)hi[6] | ((unsigned)hi[7] << 16);
    L.x = (unsigned)lo[0] | ((unsigned)lo[1] << 16);
    L.y = (unsigned)lo[2] | ((unsigned)lo[3] << 16);
    L.z = (unsigned)lo[4] | ((unsigned)lo[5] << 16);
    L.w = (unsigned)lo[6] | ((unsigned)lo[7] << 16);
    g_efrags[(kt * 8 + dc * 2 + 0) * 64 + l] = H;
    g_efrags[(kt * 8 + dc * 2 + 1) * 64 + l] = L;
}

// W into B-fragment order, TRIPLE split (conv must be ~f32-exact):
// lane l holds W[c = cb*32 + (l>>4)*8 + j][d = db*16 + (l&15)], s3 = 0/1/2
__global__ void vq_prepw(const float* __restrict__ conv_w) {
    int cb = blockIdx.x >> 3, db = blockIdx.x & 7, l = threadIdx.x;
    int c0 = cb * 32 + (l >> 4) * 8, d = db * 16 + (l & 15);
    short s1[8], s2[8], s3[8];
    #pragma unroll
    for (int j = 0; j < 8; ++j)
        split3(conv_w[(size_t)(c0 + j) * D + d], s1[j], s2[j], s3[j]);
    uint4 P[3];
    #pragma unroll
    for (int s = 0; s < 3; ++s) {
        const short* sp = s == 0 ? s1 : s == 1 ? s2 : s3;
        P[s].x = (unsigned)(unsigned short)sp[0] | ((unsigned)(unsigned short)sp[1] << 16);
        P[s].y = (unsigned)(unsigned short)sp[2] | ((unsigned)(unsigned short)sp[3] << 16);
        P[s].z = (unsigned)(unsigned short)sp[4] | ((unsigned)(unsigned short)sp[5] << 16);
        P[s].w = (unsigned)(unsigned short)sp[6] | ((unsigned)(unsigned short)sp[7] << 16);
        g_wfrags[((cb * 8 + db) * 3 + s) * 64 + l] = P[s];
    }
}

#define MFMA(a, bb, c) __builtin_amdgcn_mfma_f32_16x16x32_bf16(a, bb, c, 0, 0, 0)

__global__ __launch_bounds__(256, 2) void vq_main(
    const float* __restrict__ x, const float* __restrict__ conv_b,
    float* __restrict__ out)
{
    __shared__ uint4 ebuf[4096];            // 65536 B : double-buffered e-frag chunks
    __shared__ float e2_s[K];               // 4096 B
    __shared__ float tbuf[4 * 16 * 36];     // 9216 B : per-wave transpose bounce [16][36]
    __shared__ int   ks_s[MT];
    __shared__ float red_s[4];

    const int t    = threadIdx.x;
    const int lane = t & 63;
    const int w    = t >> 6;
    const int wg   = blockIdx.x;
    const int n0   = wg * MT;
    const int b    = n0 >> 12;
    const int hw0  = n0 & 4095;
    const int pxb  = w * 32;
    const int lp   = lane & 15;
    const int lg   = lane >> 4;

    for (int k = t; k < K; k += 256) e2_s[k] = g_scratch[16 + k];

    // -------- Phase 1: z = x^T W + bias via MFMA, TRIPLE split (6 products) --------
    f32x4 Cz[2][8];                         // C tiles [rb][db]: row px, col d
    #pragma unroll
    for (int db = 0; db < 8; ++db) {
        float bv = conv_b[db * 16 + lp];
        Cz[0][db] = (f32x4){bv, bv, bv, bv};
        Cz[1][db] = Cz[0][db];
    }
    {
        const float* xl = x + (size_t)b * CIN * HW + (size_t)(lg * 8) * HW
                          + hw0 + pxb + lp;
        for (int cb = 0; cb < 8; ++cb) {
            bf16x8 X1[2], X2[2], X3[2];
            #pragma unroll
            for (int rb = 0; rb < 2; ++rb) {
                float v[8];
                #pragma unroll
                for (int j = 0; j < 8; ++j)
                    v[j] = xl[(size_t)(cb * 32 + j) * HW + rb * 16];
                #pragma unroll
                for (int j = 0; j < 8; ++j) {
                    short a, bb, c;
                    split3(v[j], a, bb, c);
                    X1[rb][j] = a; X2[rb][j] = bb; X3[rb][j] = c;
                }
            }
            #pragma unroll
            for (int db = 0; db < 8; ++db) {
                bf16x8 W1 = *(const bf16x8*)&g_wfrags[((cb * 8 + db) * 3 + 0) * 64 + lane];
                bf16x8 W2 = *(const bf16x8*)&g_wfrags[((cb * 8 + db) * 3 + 1) * 64 + lane];
                bf16x8 W3 = *(const bf16x8*)&g_wfrags[((cb * 8 + db) * 3 + 2) * 64 + lane];
                Cz[0][db] = MFMA(X1[0], W1, Cz[0][db]);
                Cz[1][db] = MFMA(X1[1], W1, Cz[1][db]);
                Cz[0][db] = MFMA(X1[0], W2, Cz[0][db]);
                Cz[1][db] = MFMA(X1[1], W2, Cz[1][db]);
                Cz[0][db] = MFMA(X2[0], W1, Cz[0][db]);
                Cz[1][db] = MFMA(X2[1], W1, Cz[1][db]);
                Cz[0][db] = MFMA(X1[0], W3, Cz[0][db]);
                Cz[1][db] = MFMA(X1[1], W3, Cz[1][db]);
                Cz[0][db] = MFMA(X2[0], W2, Cz[0][db]);
                Cz[1][db] = MFMA(X2[1], W2, Cz[1][db]);
                Cz[0][db] = MFMA(X3[0], W1, Cz[0][db]);
                Cz[1][db] = MFMA(X3[1], W1, Cz[1][db]);
            }
        }
    }

    // ------------- Transpose C-layout -> phase-2 A-frags (wave-local) ------
    bf16x8 A2h[2][4], A2l[2][4];
    {
        float* tb = tbuf + w * 576;         // [16][36] per wave
        #pragma unroll
        for (int rb = 0; rb < 2; ++rb) {
            #pragma unroll
            for (int dc = 0; dc < 4; ++dc) {
                #pragma unroll
                for (int h = 0; h < 2; ++h)
                    #pragma unroll
                    for (int r = 0; r < 4; ++r)
                        tb[(lg * 4 + r) * 36 + h * 16 + lp] = Cz[rb][dc * 2 + h][r];
                asm volatile("s_waitcnt lgkmcnt(0)" ::: "memory");
                f32x4 a0 = *(const f32x4*)&tb[lp * 36 + lg * 8];
                f32x4 a1 = *(const f32x4*)&tb[lp * 36 + lg * 8 + 4];
                #pragma unroll
                for (int j = 0; j < 8; ++j) {
                    float zv = -2.0f * (j < 4 ? a0[j] : a1[j - 4]);
                    unsigned short hb = f2bf(zv);
                    A2h[rb][dc][j] = (short)hb;
                    A2l[rb][dc][j] = (short)f2bf(zv - bf2f(hb));
                }
                asm volatile("s_waitcnt lgkmcnt(0)" ::: "memory");
            }
        }
    }

    // ---------------- Phase 2: MFMA distance + top-2 argmin ----------------
    const uint4* gfr = g_efrags;
    {   // STAGE chunk 0 (4 kt = 2048 uint4 = 32 KB)
        uint4 tmp[8];
        #pragma unroll
        for (int i = 0; i < 8; ++i) tmp[i] = gfr[i * 256 + t];
        #pragma unroll
        for (int i = 0; i < 8; ++i) ebuf[i * 256 + t] = tmp[i];
    }
    __syncthreads();

    float v1[8], v2[8]; int i1[8], i2[8];
    #pragma unroll
    for (int q = 0; q < 8; ++q) { v1[q] = 3.4e38f; v2[q] = 3.4e38f; i1[q] = 0; i2[q] = 0; }

    for (int c = 0; c < 16; ++c) {
        uint4 tmp[8];
        if (c < 15) {
            #pragma unroll
            for (int i = 0; i < 8; ++i) tmp[i] = gfr[(c + 1) * 2048 + i * 256 + t];
        }
        const bf16x8* eb = (const bf16x8*)&ebuf[(c & 1) * 2048];
        #pragma unroll
        for (int ktl = 0; ktl < 4; ++ktl) {
            int kt = c * 4 + ktl;
            bf16x8 Bh[4], Bl[4];
            #pragma unroll
            for (int dc = 0; dc < 4; ++dc) {
                Bh[dc] = eb[(ktl * 8 + dc * 2 + 0) * 64 + lane];
                Bl[dc] = eb[(ktl * 8 + dc * 2 + 1) * 64 + lane];
            }
            float e2v = e2_s[kt * 16 + lp];
            f32x4 C0 = (f32x4){e2v, e2v, e2v, e2v};
            f32x4 C1 = C0;
            #pragma unroll
            for (int dc = 0; dc < 4; ++dc) {
                C0 = MFMA(A2h[0][dc], Bh[dc], C0);
                C1 = MFMA(A2h[1][dc], Bh[dc], C1);
                C0 = MFMA(A2l[0][dc], Bh[dc], C0);
                C1 = MFMA(A2l[1][dc], Bh[dc], C1);
                C0 = MFMA(A2h[0][dc], Bl[dc], C0);
                C1 = MFMA(A2h[1][dc], Bl[dc], C1);
            }
            int kk = kt * 16 + lp;
            #pragma unroll
            for (int rb = 0; rb < 2; ++rb) {
                f32x4 C = rb ? C1 : C0;
                #pragma unroll
                for (int r = 0; r < 4; ++r) {
                    int q = rb * 4 + r;
                    float s = C[r];
                    bool lt1 = s < v1[q], lt2 = s < v2[q];
                    v2[q] = lt1 ? v1[q] : (lt2 ? s  : v2[q]);
                    i2[q] = lt1 ? i1[q] : (lt2 ? kk : i2[q]);
                    v1[q] = lt1 ? s  : v1[q];
                    i1[q] = lt1 ? kk : i1[q];
                }
            }
        }
        if (c < 15) {
            #pragma unroll
            for (int i = 0; i < 8; ++i) ebuf[((c + 1) & 1) * 2048 + i * 256 + t] = tmp[i];
        }
        __syncthreads();
    }

    // exact top-2 merge across the 16 k-lanes (butterfly -> all lanes converge)
    #pragma unroll
    for (int off = 1; off < 16; off <<= 1) {
        #pragma unroll
        for (int q = 0; q < 8; ++q) {
            float b1 = __shfl_xor(v1[q], off); int bi1 = __shfl_xor(i1[q], off);
            float b2 = __shfl_xor(v2[q], off); int bi2 = __shfl_xor(i2[q], off);
            bool bf = (b1 < v1[q]) || (b1 == v1[q] && bi1 < i1[q]);
            float cv = bf ? v1[q] : b1;  int ci = bf ? i1[q] : bi1;
            float wv = bf ? b2 : v2[q];  int wi = bf ? bi2 : i2[q];
            v1[q] = bf ? b1 : v1[q];     i1[q] = bf ? bi1 : i1[q];
            bool c2 = (cv < wv) || (cv == wv && ci < wi);
            v2[q] = c2 ? cv : wv;        i2[q] = c2 ? ci : wi;
        }
    }

    // --------- Exact f32 refinement + diff in C-layout (true f32 Cz) -------
    float dacc = 0.0f;
    #pragma unroll
    for (int q = 0; q < 8; ++q) {
        const int rb = q >> 2, r = q & 3;
        const int k1 = i1[q], k2 = i2[q];
        float s1 = 0.0f, s2 = 0.0f;
        #pragma unroll
        for (int db = 0; db < 8; ++db) {
            float zv = Cz[rb][db][r];
            s1 += zv * g_embedT[(size_t)k1 * D + db * 16 + lp];
            s2 += zv * g_embedT[(size_t)k2 * D + db * 16 + lp];
        }
        #pragma unroll
        for (int off = 1; off < 16; off <<= 1) {
            s1 += __shfl_xor(s1, off);
            s2 += __shfl_xor(s2, off);
        }
        float d1 = e2_s[k1] - 2.0f * s1;
        float d2 = e2_s[k2] - 2.0f * s2;
        bool p2 = (d2 < d1) || (d2 == d1 && k2 < k1);
        int ks = p2 ? k2 : k1;
        #pragma unroll
        for (int db = 0; db < 8; ++db) {
            float zv = Cz[rb][db][r];
            float qv = g_embedT[(size_t)ks * D + db * 16 + lp];
            float df = qv - zv;
            dacc += df * df;
        }
        if (lp == 0) {
            int px = pxb + rb * 16 + lg * 4 + r;
            ks_s[px] = ks;
            out[IDX_OFF + n0 + px] = (float)ks;
        }
    }
    #pragma unroll
    for (int off = 1; off <= 32; off <<= 1) dacc += __shfl_xor(dacc, off);
    if (lane == 0) red_s[w] = dacc;
    __syncthreads();

    // ---------------- Epilogue: gather quantize, transpose-write -----------
    {
        int px = t & 127, half = t >> 7;
        int ks = ks_s[px];
        const f32x4* ep = (const f32x4*)&g_embedT[(size_t)ks * D + half * 64];
        float* ob = out + (size_t)b * D * HW + hw0 + px;
        #pragma unroll
        for (int d4 = 0; d4 < 16; ++d4) {
            f32x4 q4 = ep[d4];
            int d = half * 64 + d4 * 4;
            #pragma unroll
            for (int cc = 0; cc < 4; ++cc)
                ob[(size_t)(d + cc) * HW] = q4[cc];
        }
    }
    if (t == 0) atomicAdd(&g_scratch[0], red_s[0] + red_s[1] + red_s[2] + red_s[3]);
}

__global__ void vq_final(float* __restrict__ out) {
    out[DIFF_OFF] = g_scratch[0] / 8388608.0f;
}

extern "C" void kernel_launch(void* const* d_in, const int* in_sizes, int n_in,
                              void* d_out, int out_size, void* d_ws, size_t ws_size,
                              hipStream_t stream) {
    const float* x      = (const float*)d_in[0];
    const float* conv_w = (const float*)d_in[1];
    const float* conv_b = (const float*)d_in[2];
    const float* embed  = (const float*)d_in[3];
    float* out = (float*)d_out;

    vq_init  <<<4,   256, 0, stream>>>(embed);
    vq_prep2 <<<128, 256, 0, stream>>>(embed);
    vq_prep  <<<256, 64,  0, stream>>>(embed);
    vq_prepw <<<64,  64,  0, stream>>>(conv_w);
    vq_main  <<<512, 256, 0, stream>>>(x, conv_b, out);
    vq_final <<<1,   1,   0, stream>>>(out);
}

// Round 6
// 102.203 us; speedup vs baseline: 3.7371x; 1.0197x over previous
//
#include <hip/hip_runtime.h>

typedef __attribute__((ext_vector_type(4))) float f32x4;
typedef __attribute__((ext_vector_type(8))) short bf16x8;

constexpr int CIN = 256;
constexpr int D   = 128;
constexpr int K   = 1024;
constexpr int HW  = 4096;    // 64*64
constexpr int MT  = 128;     // pixels per workgroup -> 512 wgs (2/CU exactly)
constexpr int DIFF_OFF = 8388608;
constexpr int IDX_OFF  = 8388609;

// static device scratch
__device__ float g_scratch[16 + K];                       // [0]=diff acc, [16+k]=||e_k||^2
__device__ __align__(16) uint4 g_efrags[64 * 8 * 64];     // e B-frags [kt][dc*2+s][lane]
__device__ __align__(16) uint4 g_wfrags[8 * 8 * 3 * 64];  // W B-frags [cb][db][s3][lane]
__device__ __align__(16) float g_embedT[K * D];           // embed transposed [K][D]

__device__ inline unsigned short f2bf(float f) {          // f32 -> bf16 RNE
    unsigned u = __float_as_uint(f);
    u = u + 0x7fff + ((u >> 16) & 1);
    return (unsigned short)(u >> 16);
}
__device__ inline float bf2f(unsigned short h) {
    return __uint_as_float(((unsigned)h) << 16);
}
// triple split: v = a + b + c with residual ~2^-24 |v|
__device__ inline void split3(float v, short& a, short& b, short& c) {
    unsigned short h = f2bf(v); float r1 = v - bf2f(h);
    unsigned short m = f2bf(r1); float r2 = r1 - bf2f(m);
    a = (short)h; b = (short)m; c = (short)f2bf(r2);
}

// async global->LDS, 16B per lane; lds dest = wave-uniform base + lane*16
__device__ inline void gload_lds16(const uint4* g, uint4* l) {
    __builtin_amdgcn_global_load_lds(
        (const __attribute__((address_space(1))) unsigned int*)g,
        (__attribute__((address_space(3))) unsigned int*)l,
        16, 0, 0);
}

__global__ void vq_init(const float* __restrict__ embed) {
    int k = blockIdx.x * 256 + threadIdx.x;
    if (k == 0) g_scratch[0] = 0.0f;
    if (k < K) {
        float s = 0.0f;
        for (int d = 0; d < D; ++d) { float v = embed[d * K + k]; s += v * v; }
        g_scratch[16 + k] = s;
    }
}

// embedT via LDS-tiled transpose (coalesced read AND write)
__global__ void vq_prep2(const float* __restrict__ embed) {
    __shared__ float tile[32][33];
    int kb = blockIdx.x >> 2, db = blockIdx.x & 3;
    int t = threadIdx.x, tk = t & 31, td = t >> 5;
    #pragma unroll
    for (int dd = 0; dd < 4; ++dd)
        tile[td * 4 + dd][tk] = embed[(size_t)(db * 32 + td * 4 + dd) * K + kb * 32 + tk];
    __syncthreads();
    #pragma unroll
    for (int dd = 0; dd < 4; ++dd)
        g_embedT[(size_t)(kb * 32 + td * 4 + dd) * D + db * 32 + tk] = tile[tk][td * 4 + dd];
}

// e into MFMA B-fragment order, hi/lo bf16 split (2-way; approx pass only)
// Frag (kt,dc,s): lane l holds e[d = dc*32 + (l>>4)*8 + j][k = kt*16 + (l&15)]
__global__ void vq_prep(const float* __restrict__ embed) {
    int kt = blockIdx.x >> 2, dc = blockIdx.x & 3;
    int l  = threadIdx.x;
    int k  = kt * 16 + (l & 15);
    int d0 = dc * 32 + (l >> 4) * 8;
    unsigned short hi[8], lo[8];
    #pragma unroll
    for (int j = 0; j < 8; ++j) {
        float v = embed[(size_t)(d0 + j) * K + k];
        hi[j] = f2bf(v);
        lo[j] = f2bf(v - bf2f(hi[j]));
    }
    uint4 H, L;
    H.x = (unsigned)hi[0] | ((unsigned)hi[1] << 16);
    H.y = (unsigned)hi[2] | ((unsigned)hi[3] << 16);
    H.z = (unsigned)hi[4] | ((unsigned)hi[5] << 16);
    H.w = (unsigned)hi[6] | ((unsigned)hi[7] << 16);
    L.x = (unsigned)lo[0] | ((unsigned)lo[1] << 16);
    L.y = (unsigned)lo[2] | ((unsigned)lo[3] << 16);
    L.z = (unsigned)lo[4] | ((unsigned)lo[5] << 16);
    L.w = (unsigned)lo[6] | ((unsigned)lo[7] << 16);
    g_efrags[(kt * 8 + dc * 2 + 0) * 64 + l] = H;
    g_efrags[(kt * 8 + dc * 2 + 1) * 64 + l] = L;
}

// W into B-fragment order, TRIPLE split (conv must be ~f32-exact):
// lane l holds W[c = cb*32 + (l>>4)*8 + j][d = db*16 + (l&15)], s3 = 0/1/2
__global__ void vq_prepw(const float* __restrict__ conv_w) {
    int cb = blockIdx.x >> 3, db = blockIdx.x & 7, l = threadIdx.x;
    int c0 = cb * 32 + (l >> 4) * 8, d = db * 16 + (l & 15);
    short s1[8], s2[8], s3[8];
    #pragma unroll
    for (int j = 0; j < 8; ++j)
        split3(conv_w[(size_t)(c0 + j) * D + d], s1[j], s2[j], s3[j]);
    #pragma unroll
    for (int s = 0; s < 3; ++s) {
        const short* sp = s == 0 ? s1 : s == 1 ? s2 : s3;
        uint4 P;
        P.x = (unsigned)(unsigned short)sp[0] | ((unsigned)(unsigned short)sp[1] << 16);
        P.y = (unsigned)(unsigned short)sp[2] | ((unsigned)(unsigned short)sp[3] << 16);
        P.z = (unsigned)(unsigned short)sp[4] | ((unsigned)(unsigned short)sp[5] << 16);
        P.w = (unsigned)(unsigned short)sp[6] | ((unsigned)(unsigned short)sp[7] << 16);
        g_wfrags[((cb * 8 + db) * 3 + s) * 64 + l] = P;
    }
}

#define MFMA(a, bb, c) __builtin_amdgcn_mfma_f32_16x16x32_bf16(a, bb, c, 0, 0, 0)

__global__ __launch_bounds__(256, 2) void vq_main(
    const float* __restrict__ x, const float* __restrict__ conv_b,
    float* __restrict__ out)
{
    // ebuf: phase 1 = W-frag double buffer (2x1536 uint4); phase 2 = e-frag dbuf (2x2048)
    __shared__ __align__(16) uint4 ebuf[4096];      // 65536 B
    __shared__ float e2_s[K];                       // 4096 B
    __shared__ float tbuf[4 * 16 * 36];             // 9216 B per-wave transpose bounce
    __shared__ int   ks_s[MT];
    __shared__ float red_s[4];

    const int t    = threadIdx.x;
    const int lane = t & 63;
    const int w    = t >> 6;
    const int wg   = blockIdx.x;
    const int n0   = wg * MT;
    const int b    = n0 >> 12;
    const int hw0  = n0 & 4095;
    const int pxb  = w * 32;
    const int lp   = lane & 15;
    const int lg   = lane >> 4;

    for (int k = t; k < K; k += 256) e2_s[k] = g_scratch[16 + k];

    // -------- Phase 1: z = x^T W + bias via MFMA, TRIPLE split (6 products) -----
    f32x4 Cz[2][8];                         // C tiles [rb][db]: row px, col d
    #pragma unroll
    for (int db = 0; db < 8; ++db) {
        float bv = conv_b[db * 16 + lp];
        Cz[0][db] = (f32x4){bv, bv, bv, bv};
        Cz[1][db] = Cz[0][db];
    }
    {
        // prologue: DMA-stage W chunk cb=0 into ebuf[0..1535]
        #pragma unroll
        for (int i = 0; i < 6; ++i)
            gload_lds16(&g_wfrags[(w * 6 + i) * 64 + lane], &ebuf[(w * 6 + i) * 64]);
        asm volatile("s_waitcnt vmcnt(0)" ::: "memory");
        __syncthreads();

        const float* xl = x + (size_t)b * CIN * HW + (size_t)(lg * 8) * HW
                          + hw0 + pxb + lp;
        for (int cb = 0; cb < 8; ++cb) {
            // x loads FIRST (so their waitcnt doesn't drain the W-DMA below)
            float v[2][8];
            #pragma unroll
            for (int rb = 0; rb < 2; ++rb)
                #pragma unroll
                for (int j = 0; j < 8; ++j)
                    v[rb][j] = xl[(size_t)(cb * 32 + j) * HW + rb * 16];
            // issue next W chunk DMA (flies during split + MFMA)
            if (cb < 7) {
                const uint4* wsrc = g_wfrags + (size_t)(cb + 1) * 1536;
                uint4* wdst = ebuf + ((cb + 1) & 1) * 1536;
                #pragma unroll
                for (int i = 0; i < 6; ++i)
                    gload_lds16(&wsrc[(w * 6 + i) * 64 + lane], &wdst[(w * 6 + i) * 64]);
            }
            bf16x8 X1[2], X2[2], X3[2];
            #pragma unroll
            for (int rb = 0; rb < 2; ++rb)
                #pragma unroll
                for (int j = 0; j < 8; ++j) {
                    short a, bb, c;
                    split3(v[rb][j], a, bb, c);
                    X1[rb][j] = a; X2[rb][j] = bb; X3[rb][j] = c;
                }
            const uint4* wb = ebuf + (cb & 1) * 1536;
            #pragma unroll
            for (int db = 0; db < 8; ++db) {
                bf16x8 W1 = *(const bf16x8*)&wb[(db * 3 + 0) * 64 + lane];
                bf16x8 W2 = *(const bf16x8*)&wb[(db * 3 + 1) * 64 + lane];
                bf16x8 W3 = *(const bf16x8*)&wb[(db * 3 + 2) * 64 + lane];
                Cz[0][db] = MFMA(X1[0], W1, Cz[0][db]);
                Cz[1][db] = MFMA(X1[1], W1, Cz[1][db]);
                Cz[0][db] = MFMA(X1[0], W2, Cz[0][db]);
                Cz[1][db] = MFMA(X1[1], W2, Cz[1][db]);
                Cz[0][db] = MFMA(X2[0], W1, Cz[0][db]);
                Cz[1][db] = MFMA(X2[1], W1, Cz[1][db]);
                Cz[0][db] = MFMA(X1[0], W3, Cz[0][db]);
                Cz[1][db] = MFMA(X1[1], W3, Cz[1][db]);
                Cz[0][db] = MFMA(X2[0], W2, Cz[0][db]);
                Cz[1][db] = MFMA(X2[1], W2, Cz[1][db]);
                Cz[0][db] = MFMA(X3[0], W1, Cz[0][db]);
                Cz[1][db] = MFMA(X3[1], W1, Cz[1][db]);
            }
            asm volatile("s_waitcnt vmcnt(0)" ::: "memory");
            __syncthreads();
        }
    }

    // ------------- Transpose C-layout -> phase-2 A-frags (wave-local) ------
    bf16x8 A2h[2][4], A2l[2][4];
    {
        float* tb = tbuf + w * 576;         // [16][36] per wave
        #pragma unroll
        for (int rb = 0; rb < 2; ++rb) {
            #pragma unroll
            for (int dc = 0; dc < 4; ++dc) {
                #pragma unroll
                for (int h = 0; h < 2; ++h)
                    #pragma unroll
                    for (int r = 0; r < 4; ++r)
                        tb[(lg * 4 + r) * 36 + h * 16 + lp] = Cz[rb][dc * 2 + h][r];
                asm volatile("s_waitcnt lgkmcnt(0)" ::: "memory");
                f32x4 a0 = *(const f32x4*)&tb[lp * 36 + lg * 8];
                f32x4 a1 = *(const f32x4*)&tb[lp * 36 + lg * 8 + 4];
                #pragma unroll
                for (int j = 0; j < 8; ++j) {
                    float zv = -2.0f * (j < 4 ? a0[j] : a1[j - 4]);
                    unsigned short hb = f2bf(zv);
                    A2h[rb][dc][j] = (short)hb;
                    A2l[rb][dc][j] = (short)f2bf(zv - bf2f(hb));
                }
                asm volatile("s_waitcnt lgkmcnt(0)" ::: "memory");
            }
        }
    }

    // ---------------- Phase 2: MFMA distance + top-2 argmin ----------------
    const uint4* gfr = g_efrags;
    {   // DMA-stage chunk 0 (4 kt = 2048 uint4 = 32 KB)
        #pragma unroll
        for (int i = 0; i < 8; ++i)
            gload_lds16(&gfr[(w * 8 + i) * 64 + lane], &ebuf[(w * 8 + i) * 64]);
        asm volatile("s_waitcnt vmcnt(0)" ::: "memory");
        __syncthreads();
    }

    float v1[8], v2[8]; int i1[8], i2[8];
    #pragma unroll
    for (int q = 0; q < 8; ++q) { v1[q] = 3.4e38f; v2[q] = 3.4e38f; i1[q] = 0; i2[q] = 0; }

    for (int c = 0; c < 16; ++c) {
        if (c < 15) {                       // issue next-chunk DMA before compute
            const uint4* esrc = gfr + (size_t)(c + 1) * 2048;
            uint4* edst = ebuf + ((c + 1) & 1) * 2048;
            #pragma unroll
            for (int i = 0; i < 8; ++i)
                gload_lds16(&esrc[(w * 8 + i) * 64 + lane], &edst[(w * 8 + i) * 64]);
        }
        const bf16x8* eb = (const bf16x8*)&ebuf[(c & 1) * 2048];
        #pragma unroll
        for (int ktl = 0; ktl < 4; ++ktl) {
            int kt = c * 4 + ktl;
            bf16x8 Bh[4], Bl[4];
            #pragma unroll
            for (int dc = 0; dc < 4; ++dc) {
                Bh[dc] = eb[(ktl * 8 + dc * 2 + 0) * 64 + lane];
                Bl[dc] = eb[(ktl * 8 + dc * 2 + 1) * 64 + lane];
            }
            float e2v = e2_s[kt * 16 + lp];
            f32x4 C0 = (f32x4){e2v, e2v, e2v, e2v};
            f32x4 C1 = C0;
            __builtin_amdgcn_s_setprio(1);
            #pragma unroll
            for (int dc = 0; dc < 4; ++dc) {
                C0 = MFMA(A2h[0][dc], Bh[dc], C0);
                C1 = MFMA(A2h[1][dc], Bh[dc], C1);
                C0 = MFMA(A2l[0][dc], Bh[dc], C0);
                C1 = MFMA(A2l[1][dc], Bh[dc], C1);
                C0 = MFMA(A2h[0][dc], Bl[dc], C0);
                C1 = MFMA(A2h[1][dc], Bl[dc], C1);
            }
            __builtin_amdgcn_s_setprio(0);
            int kk = kt * 16 + lp;
            #pragma unroll
            for (int rb = 0; rb < 2; ++rb) {
                f32x4 C = rb ? C1 : C0;
                #pragma unroll
                for (int r = 0; r < 4; ++r) {
                    int q = rb * 4 + r;
                    float s = C[r];
                    bool lt1 = s < v1[q], lt2 = s < v2[q];
                    v2[q] = lt1 ? v1[q] : (lt2 ? s  : v2[q]);
                    i2[q] = lt1 ? i1[q] : (lt2 ? kk : i2[q]);
                    v1[q] = lt1 ? s  : v1[q];
                    i1[q] = lt1 ? kk : i1[q];
                }
            }
        }
        if (c < 15) asm volatile("s_waitcnt vmcnt(0)" ::: "memory");
        __syncthreads();
    }

    // exact top-2 merge across the 16 k-lanes (butterfly -> all lanes converge)
    #pragma unroll
    for (int off = 1; off < 16; off <<= 1) {
        #pragma unroll
        for (int q = 0; q < 8; ++q) {
            float b1 = __shfl_xor(v1[q], off); int bi1 = __shfl_xor(i1[q], off);
            float b2 = __shfl_xor(v2[q], off); int bi2 = __shfl_xor(i2[q], off);
            bool bf = (b1 < v1[q]) || (b1 == v1[q] && bi1 < i1[q]);
            float cv = bf ? v1[q] : b1;  int ci = bf ? i1[q] : bi1;
            float wv = bf ? b2 : v2[q];  int wi = bf ? bi2 : i2[q];
            v1[q] = bf ? b1 : v1[q];     i1[q] = bf ? bi1 : i1[q];
            bool c2 = (cv < wv) || (cv == wv && ci < wi);
            v2[q] = c2 ? cv : wv;        i2[q] = c2 ? ci : wi;
        }
    }

    // --------- Exact f32 refinement + diff in C-layout (true f32 Cz) -------
    float dacc = 0.0f;
    #pragma unroll
    for (int q = 0; q < 8; ++q) {
        const int rb = q >> 2, r = q & 3;
        const int k1 = i1[q], k2 = i2[q];
        float s1 = 0.0f, s2 = 0.0f;
        #pragma unroll
        for (int db = 0; db < 8; ++db) {
            float zv = Cz[rb][db][r];
            s1 += zv * g_embedT[(size_t)k1 * D + db * 16 + lp];
            s2 += zv * g_embedT[(size_t)k2 * D + db * 16 + lp];
        }
        #pragma unroll
        for (int off = 1; off < 16; off <<= 1) {
            s1 += __shfl_xor(s1, off);
            s2 += __shfl_xor(s2, off);
        }
        float d1 = e2_s[k1] - 2.0f * s1;
        float d2 = e2_s[k2] - 2.0f * s2;
        bool p2 = (d2 < d1) || (d2 == d1 && k2 < k1);
        int ks = p2 ? k2 : k1;
        #pragma unroll
        for (int db = 0; db < 8; ++db) {
            float zv = Cz[rb][db][r];
            float qv = g_embedT[(size_t)ks * D + db * 16 + lp];
            float df = qv - zv;
            dacc += df * df;
        }
        if (lp == 0) {
            int px = pxb + rb * 16 + lg * 4 + r;
            ks_s[px] = ks;
            out[IDX_OFF + n0 + px] = (float)ks;
        }
    }
    #pragma unroll
    for (int off = 1; off <= 32; off <<= 1) dacc += __shfl_xor(dacc, off);
    if (lane == 0) red_s[w] = dacc;
    __syncthreads();

    // ---------------- Epilogue: gather quantize, transpose-write -----------
    {
        int px = t & 127, half = t >> 7;
        int ks = ks_s[px];
        const f32x4* ep = (const f32x4*)&g_embedT[(size_t)ks * D + half * 64];
        float* ob = out + (size_t)b * D * HW + hw0 + px;
        #pragma unroll
        for (int d4 = 0; d4 < 16; ++d4) {
            f32x4 q4 = ep[d4];
            int d = half * 64 + d4 * 4;
            #pragma unroll
            for (int cc = 0; cc < 4; ++cc)
                ob[(size_t)(d + cc) * HW] = q4[cc];
        }
    }
    if (t == 0) atomicAdd(&g_scratch[0], red_s[0] + red_s[1] + red_s[2] + red_s[3]);
}

__global__ void vq_final(float* __restrict__ out) {
    out[DIFF_OFF] = g_scratch[0] / 8388608.0f;
}

extern "C" void kernel_launch(void* const* d_in, const int* in_sizes, int n_in,
                              void* d_out, int out_size, void* d_ws, size_t ws_size,
                              hipStream_t stream) {
    const float* x      = (const float*)d_in[0];
    const float* conv_w = (const float*)d_in[1];
    const float* conv_b = (const float*)d_in[2];
    const float* embed  = (const float*)d_in[3];
    float* out = (float*)d_out;

    vq_init  <<<4,   256, 0, stream>>>(embed);
    vq_prep2 <<<128, 256, 0, stream>>>(embed);
    vq_prep  <<<256, 64,  0, stream>>>(embed);
    vq_prepw <<<64,  64,  0, stream>>>(conv_w);
    vq_main  <<<512, 256, 0, stream>>>(x, conv_b, out);
    vq_final <<<1,   1,   0, stream>>>(out);
}